// Round 2
// 1169.767 us; speedup vs baseline: 1.2818x; 1.2818x over previous
//
#include <hip/hip_runtime.h>

// APPNP: h = relu(x@W0+b0)@W1+b1 ; z0=h ; z_{k+1} = 0.9 * (Ahat z_k) + 0.1 * h  (10 iters)
// Ahat = D^-1/2 (A + I) D^-1/2, deg by source(row) incl. self-loop weight 1.
//
// R2: device-scope atomics are memory-side (~23G/s fixed) -> eliminated (paged LDS hist).
// R3 finding: paged kernels were grid-starved (224 blocks, Occupancy 9.4%, VALU 5%).
// R4: BPP 32->64 (448 blocks); k_prop unroll 8; zb buffers overlaid on dead slab region.
// R5: srcw packed to 4B/edge: (src<<15)|bf16(dinv[src]*ew) -- src needs 17b (N<131072),
//     weight is nonneg so sign-free bf16 = 15b; dinv[dest] factored out, applied once
//     per dest in prop epilogue. Halves k_scat scatter payload + prop srcw stream.
//     h kept bf16-only (mlp writes bf16, k_h2b deleted, prop h-term reads bf16).
//     prop inner loop fully predicated unroll-8 (tail gathers clamped to end-1 ->
//     same line as last valid edge -> L1 hit, keeps 8 gathers in flight in the tail).
//     cnt slab u16 (per-block-dest counts ~3, total deg ~70 << 65536).
// R6: identical re-run of R5 -- round-1 failure was container-level infra
//     ("MI355X container failed twice", no verify/profile), source re-audited clean.

#define LDW 68     // MLP LDS pad: 68 mod 32 = 4 -> max 2-way bank aliasing (free)
#define PAGE 16128 // dests per page; 16128*4B = 63KB LDS histogram -> 2 blocks/CU
#define BPP 64     // blocks per page (each scans E/BPP edge chunk)

// ---- bf16 helpers ----
__device__ __forceinline__ float bf_lo(unsigned z) { return __uint_as_float(z << 16); }
__device__ __forceinline__ float bf_hi(unsigned z) { return __uint_as_float(z & 0xffff0000u); }
__device__ __forceinline__ unsigned bf_rne(float x) {
    unsigned u = __float_as_uint(x);
    return (u + 0x7fffu + ((u >> 16) & 1u)) >> 16;
}
__device__ __forceinline__ unsigned bf_pack(float x, float y) { return bf_rne(x) | (bf_rne(y) << 16); }

// ---- deg histogram by row (float, weighted), paged ----
__global__ __launch_bounds__(256) void k_deg(const int* __restrict__ row, const float* __restrict__ ew,
                                             float* __restrict__ slab, int E, int chunk) {
    __shared__ float hf[PAGE];
    int p = blockIdx.x / BPP, b = blockIdx.x - p * BPP;
    int lo = p * PAGE;
    for (int i = threadIdx.x; i < PAGE; i += 256) hf[i] = 0.f;
    __syncthreads();
    int e0 = b * chunk, e1 = min(e0 + chunk, E);
    int evec = e0 + ((e1 - e0) & ~3);
    for (int e = e0 + (int)threadIdx.x * 4; e + 4 <= evec; e += 1024) {
        int4 r4 = *(const int4*)(row + e);
        float4 w4 = *(const float4*)(ew + e);
        unsigned a = (unsigned)(r4.x - lo), bq = (unsigned)(r4.y - lo);
        unsigned c = (unsigned)(r4.z - lo), dq = (unsigned)(r4.w - lo);
        if (a < PAGE) atomicAdd(&hf[a], w4.x);
        if (bq < PAGE) atomicAdd(&hf[bq], w4.y);
        if (c < PAGE) atomicAdd(&hf[c], w4.z);
        if (dq < PAGE) atomicAdd(&hf[dq], w4.w);
    }
    for (int e = evec + (int)threadIdx.x; e < e1; e += 256) {
        unsigned a = (unsigned)(row[e] - lo);
        if (a < PAGE) atomicAdd(&hf[a], ew[e]);
    }
    __syncthreads();
    float* out = slab + (size_t)blockIdx.x * PAGE;
    for (int i = threadIdx.x; i < PAGE; i += 256) out[i] = hf[i];
}

__global__ __launch_bounds__(256) void k_fold_deg(const float* __restrict__ slab, float* __restrict__ dinv, int N) {
    int i = blockIdx.x * 256 + threadIdx.x;
    if (i >= N) return;
    int p = i / PAGE, ld = i - p * PAGE;
    const float* base = slab + (size_t)(p * BPP) * PAGE + ld;
    float d = 1.0f;  // self-loop weight
#pragma unroll
    for (int b = 0; b < BPP; ++b) d += base[(size_t)b * PAGE];
    dinv[i] = d > 0.f ? rsqrtf(d) : 0.f;
}

// ---- cnt histogram by col (u16 slab), paged ----
__global__ __launch_bounds__(256) void k_cnt(const int* __restrict__ col, unsigned short* __restrict__ slab,
                                             int E, int chunk) {
    __shared__ int hi[PAGE];
    int p = blockIdx.x / BPP, b = blockIdx.x - p * BPP;
    int lo = p * PAGE;
    for (int i = threadIdx.x; i < PAGE; i += 256) hi[i] = 0;
    __syncthreads();
    int e0 = b * chunk, e1 = min(e0 + chunk, E);
    int evec = e0 + ((e1 - e0) & ~3);
    for (int e = e0 + (int)threadIdx.x * 4; e + 4 <= evec; e += 1024) {
        int4 c4 = *(const int4*)(col + e);
        unsigned a = (unsigned)(c4.x - lo), bq = (unsigned)(c4.y - lo);
        unsigned c = (unsigned)(c4.z - lo), dq = (unsigned)(c4.w - lo);
        if (a < PAGE) atomicAdd(&hi[a], 1);
        if (bq < PAGE) atomicAdd(&hi[bq], 1);
        if (c < PAGE) atomicAdd(&hi[c], 1);
        if (dq < PAGE) atomicAdd(&hi[dq], 1);
    }
    for (int e = evec + (int)threadIdx.x; e < e1; e += 256) {
        unsigned a = (unsigned)(col[e] - lo);
        if (a < PAGE) atomicAdd(&hi[a], 1);
    }
    __syncthreads();
    unsigned short* out = slab + (size_t)blockIdx.x * PAGE;
    for (int i = threadIdx.x; i < PAGE; i += 256) out[i] = (unsigned short)hi[i];
}

// fold cnt: total per dest + per-block exclusive offsets written back in place (u16)
__global__ __launch_bounds__(256) void k_fold_cnt(unsigned short* __restrict__ slab, int* __restrict__ cnt, int N) {
    int i = blockIdx.x * 256 + threadIdx.x;
    if (i >= N) return;
    int p = i / PAGE, ld = i - p * PAGE;
    unsigned short* base = slab + (size_t)(p * BPP) * PAGE + ld;
    int run = 0;
#pragma unroll
    for (int b = 0; b < BPP; ++b) {
        size_t off = (size_t)b * PAGE;
        int v = base[off];
        base[off] = (unsigned short)run;
        run += v;
    }
    cnt[i] = run;
}

// ---- 3-kernel exclusive scan of cnt[N] -> rowp[N], chunk = 1024 ----
__global__ __launch_bounds__(256) void k_scanA(const int* __restrict__ cnt, int* __restrict__ csum, int N) {
    __shared__ int s[256];
    int t = threadIdx.x, base = blockIdx.x * 1024;
    int p = 0;
#pragma unroll
    for (int j = 0; j < 4; ++j) { int idx = base + t + 256 * j; if (idx < N) p += cnt[idx]; }
    s[t] = p; __syncthreads();
    for (int off = 128; off > 0; off >>= 1) { if (t < off) s[t] += s[t + off]; __syncthreads(); }
    if (t == 0) csum[blockIdx.x] = s[0];
}

__global__ __launch_bounds__(256) void k_scanB(int* __restrict__ csum, int NC) {
    __shared__ int s[256];
    int t = threadIdx.x;
    int v = (t < NC) ? csum[t] : 0;
    s[t] = v; __syncthreads();
    for (int off = 1; off < 256; off <<= 1) {
        int x = (t >= off) ? s[t - off] : 0;
        __syncthreads();
        s[t] += x; __syncthreads();
    }
    if (t < NC) csum[t] = s[t] - v;  // exclusive
}

__global__ __launch_bounds__(256) void k_scanC(const int* __restrict__ cnt, const int* __restrict__ csum,
                                               int* __restrict__ rowp, int N) {
    __shared__ int s[256];
    int t = threadIdx.x, base = blockIdx.x * 1024 + t * 4;
    int c0 = (base + 0 < N) ? cnt[base + 0] : 0;
    int c1 = (base + 1 < N) ? cnt[base + 1] : 0;
    int c2 = (base + 2 < N) ? cnt[base + 2] : 0;
    int c3 = (base + 3 < N) ? cnt[base + 3] : 0;
    int ts = c0 + c1 + c2 + c3;
    s[t] = ts; __syncthreads();
    for (int off = 1; off < 256; off <<= 1) {
        int x = (t >= off) ? s[t - off] : 0;
        __syncthreads();
        s[t] += x; __syncthreads();
    }
    int o = csum[blockIdx.x] + s[t] - ts;
    if (base + 0 < N) rowp[base + 0] = o;
    if (base + 1 < N) rowp[base + 1] = o + c0;
    if (base + 2 < N) rowp[base + 2] = o + c0 + c1;
    if (base + 3 < N) rowp[base + 3] = o + c0 + c1 + c2;
}

// ---- scatter: deterministic positions, LDS cursors only; packed 4B payload ----
// payload = (src << 15) | (bf16(dinv[src]*ew) & 0x7fff)   [w >= 0, src < 2^17]
__global__ __launch_bounds__(256) void k_scat(const int* __restrict__ row, const int* __restrict__ col,
                                              const float* __restrict__ ew, const float* __restrict__ dinv,
                                              const int* __restrict__ rowp, const unsigned short* __restrict__ slab,
                                              unsigned* __restrict__ srcw, int E, int chunk) {
    __shared__ int cur[PAGE];
    int p = blockIdx.x / BPP, b = blockIdx.x - p * BPP;
    int lo = p * PAGE;
    for (int i = threadIdx.x; i < PAGE; i += 256) cur[i] = 0;
    __syncthreads();
    const unsigned short* soff = slab + (size_t)blockIdx.x * PAGE;
    int e0 = b * chunk, e1 = min(e0 + chunk, E);
    int evec = e0 + ((e1 - e0) & ~3);
    for (int e = e0 + (int)threadIdx.x * 4; e + 4 <= evec; e += 1024) {
        int4 c4 = *(const int4*)(col + e);
        unsigned a = (unsigned)(c4.x - lo), bq = (unsigned)(c4.y - lo);
        unsigned cc = (unsigned)(c4.z - lo), dq = (unsigned)(c4.w - lo);
        if ((a < PAGE) | (bq < PAGE) | (cc < PAGE) | (dq < PAGE)) {
            int4 r4 = *(const int4*)(row + e);
            float4 w4 = *(const float4*)(ew + e);
            if (a < PAGE) {
                int pos = rowp[c4.x] + soff[a] + atomicAdd(&cur[a], 1);
                srcw[pos] = ((unsigned)r4.x << 15) | (bf_rne(dinv[r4.x] * w4.x) & 0x7fffu);
            }
            if (bq < PAGE) {
                int pos = rowp[c4.y] + soff[bq] + atomicAdd(&cur[bq], 1);
                srcw[pos] = ((unsigned)r4.y << 15) | (bf_rne(dinv[r4.y] * w4.y) & 0x7fffu);
            }
            if (cc < PAGE) {
                int pos = rowp[c4.z] + soff[cc] + atomicAdd(&cur[cc], 1);
                srcw[pos] = ((unsigned)r4.z << 15) | (bf_rne(dinv[r4.z] * w4.z) & 0x7fffu);
            }
            if (dq < PAGE) {
                int pos = rowp[c4.w] + soff[dq] + atomicAdd(&cur[dq], 1);
                srcw[pos] = ((unsigned)r4.w << 15) | (bf_rne(dinv[r4.w] * w4.w) & 0x7fffu);
            }
        }
    }
    for (int e = evec + (int)threadIdx.x; e < e1; e += 256) {
        int c = col[e];
        unsigned a = (unsigned)(c - lo);
        if (a < PAGE) {
            int r = row[e];
            int pos = rowp[c] + soff[a] + atomicAdd(&cur[a], 1);
            srcw[pos] = ((unsigned)r << 15) | (bf_rne(dinv[r] * ew[e]) & 0x7fffu);
        }
    }
}

// ---- fused 2-layer MLP: 64 rows x 64 cols per block, 4x4 register tile; bf16 output ----
__global__ __launch_bounds__(256) void k_mlp(const float* __restrict__ x,
                                             const float* __restrict__ W0, const float* __restrict__ b0,
                                             const float* __restrict__ W1, const float* __restrict__ b1,
                                             unsigned* __restrict__ hb, int N) {
    __shared__ __align__(16) float xs[64 * LDW];
    __shared__ __align__(16) float ws[64 * LDW];
    int tid = threadIdx.x;
    int tc = tid & 15, tr = tid >> 4;
    int rbase = blockIdx.x * 64;

    float acc[4][4];
#pragma unroll
    for (int i = 0; i < 4; ++i)
#pragma unroll
        for (int j = 0; j < 4; ++j) acc[i][j] = 0.f;

    for (int ck = 0; ck < 8; ++ck) {
        int k0 = ck * 64;
#pragma unroll
        for (int j = 0; j < 4; ++j) {
            int l = tid + 256 * j;
            int r = l >> 4, kq = l & 15;
            int gr = rbase + r;
            float4 v = make_float4(0.f, 0.f, 0.f, 0.f);
            if (gr < N) v = *(const float4*)(x + (size_t)gr * 512 + k0 + kq * 4);
            xs[(kq * 4 + 0) * LDW + r] = v.x;
            xs[(kq * 4 + 1) * LDW + r] = v.y;
            xs[(kq * 4 + 2) * LDW + r] = v.z;
            xs[(kq * 4 + 3) * LDW + r] = v.w;
        }
#pragma unroll
        for (int j = 0; j < 4; ++j) {
            int l = tid + 256 * j;
            int kk = l >> 4, cq = l & 15;
            *(float4*)(ws + kk * LDW + cq * 4) = *(const float4*)(W0 + (size_t)(k0 + kk) * 64 + cq * 4);
        }
        __syncthreads();
#pragma unroll 4
        for (int k = 0; k < 64; ++k) {
            float4 a = *(const float4*)(xs + k * LDW + tr * 4);
            float4 w = *(const float4*)(ws + k * LDW + tc * 4);
            acc[0][0] = fmaf(a.x, w.x, acc[0][0]); acc[0][1] = fmaf(a.x, w.y, acc[0][1]);
            acc[0][2] = fmaf(a.x, w.z, acc[0][2]); acc[0][3] = fmaf(a.x, w.w, acc[0][3]);
            acc[1][0] = fmaf(a.y, w.x, acc[1][0]); acc[1][1] = fmaf(a.y, w.y, acc[1][1]);
            acc[1][2] = fmaf(a.y, w.z, acc[1][2]); acc[1][3] = fmaf(a.y, w.w, acc[1][3]);
            acc[2][0] = fmaf(a.z, w.x, acc[2][0]); acc[2][1] = fmaf(a.z, w.y, acc[2][1]);
            acc[2][2] = fmaf(a.z, w.z, acc[2][2]); acc[2][3] = fmaf(a.z, w.w, acc[2][3]);
            acc[3][0] = fmaf(a.w, w.x, acc[3][0]); acc[3][1] = fmaf(a.w, w.y, acc[3][1]);
            acc[3][2] = fmaf(a.w, w.z, acc[3][2]); acc[3][3] = fmaf(a.w, w.w, acc[3][3]);
        }
        __syncthreads();
    }
#pragma unroll
    for (int jj = 0; jj < 4; ++jj) {
        float b = b0[tc * 4 + jj];
        float4 v;
        v.x = fmaxf(acc[0][jj] + b, 0.f);
        v.y = fmaxf(acc[1][jj] + b, 0.f);
        v.z = fmaxf(acc[2][jj] + b, 0.f);
        v.w = fmaxf(acc[3][jj] + b, 0.f);
        *(float4*)(xs + (tc * 4 + jj) * LDW + tr * 4) = v;
    }
#pragma unroll
    for (int j = 0; j < 4; ++j) {
        int l = tid + 256 * j;
        int kk = l >> 4, cq = l & 15;
        *(float4*)(ws + kk * LDW + cq * 4) = *(const float4*)(W1 + (size_t)kk * 64 + cq * 4);
    }
    float acc2[4][4];
#pragma unroll
    for (int i = 0; i < 4; ++i)
#pragma unroll
        for (int j = 0; j < 4; ++j) acc2[i][j] = 0.f;
    __syncthreads();
#pragma unroll 4
    for (int k = 0; k < 64; ++k) {
        float4 a = *(const float4*)(xs + k * LDW + tr * 4);
        float4 w = *(const float4*)(ws + k * LDW + tc * 4);
        acc2[0][0] = fmaf(a.x, w.x, acc2[0][0]); acc2[0][1] = fmaf(a.x, w.y, acc2[0][1]);
        acc2[0][2] = fmaf(a.x, w.z, acc2[0][2]); acc2[0][3] = fmaf(a.x, w.w, acc2[0][3]);
        acc2[1][0] = fmaf(a.y, w.x, acc2[1][0]); acc2[1][1] = fmaf(a.y, w.y, acc2[1][1]);
        acc2[1][2] = fmaf(a.y, w.z, acc2[1][2]); acc2[1][3] = fmaf(a.y, w.w, acc2[1][3]);
        acc2[2][0] = fmaf(a.z, w.x, acc2[2][0]); acc2[2][1] = fmaf(a.z, w.y, acc2[2][1]);
        acc2[2][2] = fmaf(a.z, w.z, acc2[2][2]); acc2[2][3] = fmaf(a.z, w.w, acc2[2][3]);
        acc2[3][0] = fmaf(a.w, w.x, acc2[3][0]); acc2[3][1] = fmaf(a.w, w.y, acc2[3][1]);
        acc2[3][2] = fmaf(a.w, w.z, acc2[3][2]); acc2[3][3] = fmaf(a.w, w.w, acc2[3][3]);
    }
    float bv0 = b1[tc * 4 + 0], bv1 = b1[tc * 4 + 1], bv2 = b1[tc * 4 + 2], bv3 = b1[tc * 4 + 3];
#pragma unroll
    for (int i = 0; i < 4; ++i) {
        int gr = rbase + tr * 4 + i;
        if (gr < N) {
            float o0 = acc2[i][0] + bv0, o1 = acc2[i][1] + bv1;
            float o2 = acc2[i][2] + bv2, o3 = acc2[i][3] + bv3;
            *(uint2*)(hb + (size_t)gr * 32 + tc * 2) = make_uint2(bf_pack(o0, o1), bf_pack(o2, o3));
        }
    }
}

// ---- propagation: wave per dest, 2 edges x 32 lanes, bf16 z gather, predicated unroll 8 ----
// srcw packed 4B: src = pk>>15, w = bits((pk&0x7fff)<<16); agg scaled by dinv[d] in epilogue.
__global__ __launch_bounds__(256) void k_prop(const unsigned* __restrict__ srcw,
                                              const int* __restrict__ rowp, const int* __restrict__ cnt,
                                              const float* __restrict__ dinv,
                                              const unsigned* __restrict__ zin, const unsigned* __restrict__ hb,
                                              unsigned* __restrict__ zout_b, float* __restrict__ zout_f, int N) {
    int wid = (blockIdx.x << 2) | (threadIdx.x >> 6);
    int d = __builtin_amdgcn_readfirstlane(wid);  // wave-uniform -> scalar loads for per-dest data
    if (d >= N) return;
    int lane = threadIdx.x & 63;
    int half = lane >> 5, fi = lane & 31;  // lane handles features (2fi, 2fi+1) of edge parity `half`
    int beg = rowp[d], end = beg + cnt[d];
    float ax = 0.f, ay = 0.f;
    for (int e = beg + half; e < end; e += 16) {  // 8 edges per parity always in flight
        unsigned pk[8];
#pragma unroll
        for (int k = 0; k < 8; ++k) {
            int idx = e + 2 * k;
            pk[k] = srcw[min(idx, end - 1)];  // clamp: dead slots re-read last valid edge (L1-hot)
        }
        unsigned z[8];
#pragma unroll
        for (int k = 0; k < 8; ++k) z[k] = zin[(pk[k] >> 15) * 32u + fi];
#pragma unroll
        for (int k = 0; k < 8; ++k) {
            float w = (e + 2 * k < end) ? __uint_as_float((pk[k] & 0x7fffu) << 16) : 0.f;
            ax = fmaf(w, bf_lo(z[k]), ax);
            ay = fmaf(w, bf_hi(z[k]), ay);
        }
    }
    ax += __shfl_xor(ax, 32);
    ay += __shfl_xor(ay, 32);
    if (half == 0) {
        float di = dinv[d];
        unsigned zs = zin[(size_t)d * 32 + fi];  // analytic self-loop
        float s2 = di * di;
        float ox = 0.9f * fmaf(di, ax, s2 * bf_lo(zs));
        float oy = 0.9f * fmaf(di, ay, s2 * bf_hi(zs));
        unsigned hz = hb[(size_t)d * 32 + fi];
        ox = fmaf(0.1f, bf_lo(hz), ox);
        oy = fmaf(0.1f, bf_hi(hz), oy);
        if (zout_f) ((float2*)zout_f)[(size_t)d * 32 + fi] = make_float2(ox, oy);
        else zout_b[(size_t)d * 32 + fi] = bf_pack(ox, oy);
    }
}

extern "C" void kernel_launch(void* const* d_in, const int* in_sizes, int n_in,
                              void* d_out, int out_size, void* d_ws, size_t ws_size,
                              hipStream_t stream) {
    const float* x  = (const float*)d_in[0];
    const int*   ei = (const int*)d_in[1];
    const float* ew = (const float*)d_in[2];
    const float* W0 = (const float*)d_in[3];
    const float* b0 = (const float*)d_in[4];
    const float* W1 = (const float*)d_in[5];
    const float* b1 = (const float*)d_in[6];
    int N = in_sizes[0] / 512;
    int E = in_sizes[2];
    const int* row = ei;
    const int* col = ei + E;

    char* p = (char*)d_ws;
    auto alloc = [&](size_t bytes) -> char* {
        char* r = p;
        p += (bytes + 255) & ~(size_t)255;
        return r;
    };
    int NPg = (N + PAGE - 1) / PAGE;                         // 7 pages for N=100K
    size_t zbytes = (size_t)N * 32 * 4;                      // 12.8 MB per bf16 z buffer
    size_t slab_bytes = (size_t)NPg * BPP * PAGE * 4;        // 28.9 MB float deg slab (hosts u16 cnt slab too)
    unsigned* hb  = (unsigned*)alloc(zbytes);                // bf16 h, persists all iters
    float* slabf  = (float*)alloc(slab_bytes);               // dead after k_scat
    unsigned* srcw = (unsigned*)alloc((size_t)E * 4);        // 12.8 MB packed edges
    float* dinv  = (float*)alloc((size_t)N * 4);
    int* cnt     = (int*)alloc((size_t)N * 4);
    int* rowp    = (int*)alloc((size_t)N * 4);
    int* csum    = (int*)alloc(512 * 4);
    unsigned short* slabu = (unsigned short*)slabf;  // sequential reuse: deg fold before k_cnt writes
    // zb0/zb1 overlay the slab region (slab dead once k_scat finishes; stream order).
    unsigned* zb0 = (unsigned*)slabf;
    unsigned* zb1 = (unsigned*)((char*)slabf + zbytes);

    int gN = (N + 255) / 256;
    int NC = (N + 1023) / 1024;
    int chunk = (((E + BPP - 1) / BPP) + 3) & ~3;
    int gridPg = NPg * BPP;

    k_deg<<<gridPg, 256, 0, stream>>>(row, ew, slabf, E, chunk);
    k_fold_deg<<<gN, 256, 0, stream>>>(slabf, dinv, N);
    k_cnt<<<gridPg, 256, 0, stream>>>(col, slabu, E, chunk);
    k_fold_cnt<<<gN, 256, 0, stream>>>(slabu, cnt, N);
    k_scanA<<<NC, 256, 0, stream>>>(cnt, csum, N);
    k_scanB<<<1, 256, 0, stream>>>(csum, NC);
    k_scanC<<<NC, 256, 0, stream>>>(cnt, csum, rowp, N);
    k_scat<<<gridPg, 256, 0, stream>>>(row, col, ew, dinv, rowp, slabu, srcw, E, chunk);
    k_mlp<<<(N + 63) / 64, 256, 0, stream>>>(x, W0, b0, W1, b1, hb, N);

    unsigned* zbufs[2] = { zb0, zb1 };  // iter it writes zbufs[it&1] (bf16) except final
    const unsigned* zi = hb;            // z0 = bf16(h), no conversion kernel needed
    int gP = (N + 3) / 4;
    for (int it = 0; it < 10; ++it) {
        if (it < 9) {
            unsigned* zo = zbufs[it & 1];
            k_prop<<<gP, 256, 0, stream>>>(srcw, rowp, cnt, dinv, zi, hb, zo, nullptr, N);
            zi = zo;
        } else {
            k_prop<<<gP, 256, 0, stream>>>(srcw, rowp, cnt, dinv, zi, hb, nullptr, (float*)d_out, N);
        }
    }
}